// Round 4
// baseline (730.614 us; speedup 1.0000x reference)
//
#include <hip/hip_runtime.h>
#include <hip/hip_bf16.h>
#include <cstdint>

#define D_DIM 1024
#define H_DIM 4096
#define E_NUM 8
#define NTOK  8192

#define BM 256
#define BN 256
#define BK 64

#define MAXT 40             // worst-case row-tiles: sum ceil(ne/256) <= 39
#define NBY1 (H_DIM / BN)   // 16
#define NBY2 (D_DIM / BN)   // 4

typedef __bf16 bf16;
typedef __bf16 bf16x8 __attribute__((ext_vector_type(8)));
typedef __bf16 bf16x4 __attribute__((ext_vector_type(4)));
typedef float  f32x4  __attribute__((ext_vector_type(4)));

// global_load_lds: per-lane global src, wave-uniform LDS base + lane*16B dest
#define GLOAD16(g, l)                                                          \
    __builtin_amdgcn_global_load_lds(                                          \
        (const __attribute__((address_space(1))) void*)(g),                    \
        (__attribute__((address_space(3))) void*)(l), 16, 0, 0)

// ---- 8-phase GEMM building blocks (shared by gemm1/gemm2 via macros) ----
// LDS tiles sA/sB: [2 bufs][256 rows][64 k] bf16, linear. Half-tiles by row
// (lo = rows 0-127, hi = 128-255), staged one per phase, 2 gloads/thread.
#define STAGE_A(bf, h, tt) do {                                                \
    GLOAD16(Asrc + (size_t)((h) * 128) * K + (size_t)(tt) * BK,                \
            &sA[(bf)][((h) * 128 + (w << 3)) * BK]);                           \
    GLOAD16(Asrc + (size_t)((h) * 128 + 64) * K + (size_t)(tt) * BK,           \
            &sA[(bf)][((h) * 128 + 64 + (w << 3)) * BK]);                      \
} while (0)
#define STAGE_B(bf, h, tt) do {                                                \
    GLOAD16(Bsrc + (size_t)((h) * 128) * K + (size_t)(tt) * BK,                \
            &sB[(bf)][((h) * 128 + (w << 3)) * BK]);                           \
    GLOAD16(Bsrc + (size_t)((h) * 128 + 64) * K + (size_t)(tt) * BK,           \
            &sB[(bf)][((h) * 128 + 64 + (w << 3)) * BK]);                      \
} while (0)

// fragment loads: A row = i*32 + wr*16 + (lane&15); B row = wc*64 + j*16 + (lane&15)
#define LDA(i, kh) (*(const bf16x8*)&sA[buf][((i) * 32 + wr * 16 + l15) * BK + (kh) * 32 + q8])
#define LDB(j, kh) (*(const bf16x8*)&sB[buf][(wc * 64 + (j) * 16 + l15) * BK + (kh) * 32 + q8])

#define MM4(I, AA, B0, B1, B2, B3) do {                                        \
    acc[I][0] = __builtin_amdgcn_mfma_f32_16x16x32_bf16(AA, B0, acc[I][0], 0, 0, 0); \
    acc[I][1] = __builtin_amdgcn_mfma_f32_16x16x32_bf16(AA, B1, acc[I][1], 0, 0, 0); \
    acc[I][2] = __builtin_amdgcn_mfma_f32_16x16x32_bf16(AA, B2, acc[I][2], 0, 0, 0); \
    acc[I][3] = __builtin_amdgcn_mfma_f32_16x16x32_bf16(AA, B3, acc[I][3], 0, 0, 0); \
} while (0)

#define VMCNT2() asm volatile("s_waitcnt vmcnt(2)" ::: "memory")

// K-loop: 4 phases/tile. Stage order: ph1 A-hi(t+1), ph2 B-lo(t+1),
// ph3 B-hi(t+1), ph4 A-lo(t+2). Single vmcnt(2) at end-ph4 guarantees
// A-lo(t+1)/A-hi(t+1)/B-lo(t+1)/B-hi(t+1) landed before tile t+1's reads,
// while A-lo(t+2) stays in flight across the barrier (never drain to 0).
#define KLOOP(NT) do {                                                         \
    STAGE_A(0, 0, 0); STAGE_B(0, 0, 0); STAGE_B(0, 1, 0); STAGE_A(0, 1, 0);    \
    STAGE_A(1, 0, 1);                                                          \
    VMCNT2();                                                                  \
    __syncthreads();                                                           \
    for (int kt = 0; kt < (NT); kt++) {                                        \
        const int buf = kt & 1, ob = buf ^ 1;                                  \
        const int tp1 = (kt + 1 < (NT)) ? kt + 1 : 0;                          \
        const int tp2 = (kt + 2 < (NT)) ? kt + 2 : kt + 2 - (NT);              \
        bf16x8 a0, a1, a2, a3, bb0, bb1, bb2, bb3, cc0, cc1, cc2, cc3;         \
        /* ph1: m-frags 0-3, k-half 0 */                                       \
        a0 = LDA(0, 0); a1 = LDA(1, 0); a2 = LDA(2, 0); a3 = LDA(3, 0);        \
        bb0 = LDB(0, 0); bb1 = LDB(1, 0); bb2 = LDB(2, 0); bb3 = LDB(3, 0);    \
        STAGE_A(ob, 1, tp1);                                                   \
        __syncthreads();                                                       \
        __builtin_amdgcn_s_setprio(1);                                         \
        MM4(0, a0, bb0, bb1, bb2, bb3); MM4(1, a1, bb0, bb1, bb2, bb3);        \
        MM4(2, a2, bb0, bb1, bb2, bb3); MM4(3, a3, bb0, bb1, bb2, bb3);        \
        __builtin_amdgcn_s_setprio(0);                                         \
        __syncthreads();                                                       \
        /* ph2: m-frags 4-7, k-half 0 (B regs reused) */                       \
        a0 = LDA(4, 0); a1 = LDA(5, 0); a2 = LDA(6, 0); a3 = LDA(7, 0);        \
        STAGE_B(ob, 0, tp1);                                                   \
        __syncthreads();                                                       \
        __builtin_amdgcn_s_setprio(1);                                         \
        MM4(4, a0, bb0, bb1, bb2, bb3); MM4(5, a1, bb0, bb1, bb2, bb3);        \
        MM4(6, a2, bb0, bb1, bb2, bb3); MM4(7, a3, bb0, bb1, bb2, bb3);        \
        __builtin_amdgcn_s_setprio(0);                                         \
        __syncthreads();                                                       \
        /* ph3: m-frags 0-3, k-half 1 */                                       \
        a0 = LDA(0, 1); a1 = LDA(1, 1); a2 = LDA(2, 1); a3 = LDA(3, 1);        \
        cc0 = LDB(0, 1); cc1 = LDB(1, 1); cc2 = LDB(2, 1); cc3 = LDB(3, 1);    \
        STAGE_B(ob, 1, tp1);                                                   \
        __syncthreads();                                                       \
        __builtin_amdgcn_s_setprio(1);                                         \
        MM4(0, a0, cc0, cc1, cc2, cc3); MM4(1, a1, cc0, cc1, cc2, cc3);        \
        MM4(2, a2, cc0, cc1, cc2, cc3); MM4(3, a3, cc0, cc1, cc2, cc3);        \
        __builtin_amdgcn_s_setprio(0);                                         \
        __syncthreads();                                                       \
        /* ph4: m-frags 4-7, k-half 1 */                                       \
        a0 = LDA(4, 1); a1 = LDA(5, 1); a2 = LDA(6, 1); a3 = LDA(7, 1);        \
        STAGE_A(buf, 0, tp2);                                                  \
        __syncthreads();                                                       \
        __builtin_amdgcn_s_setprio(1);                                         \
        MM4(4, a0, cc0, cc1, cc2, cc3); MM4(5, a1, cc0, cc1, cc2, cc3);        \
        MM4(6, a2, cc0, cc1, cc2, cc3); MM4(7, a3, cc0, cc1, cc2, cc3);        \
        __builtin_amdgcn_s_setprio(0);                                         \
        VMCNT2();                                                              \
        __syncthreads();                                                       \
    }                                                                          \
} while (0)

// ---------------- gating ----------------
__global__ __launch_bounds__(64) void gate_kernel(
    const float* __restrict__ x, const float* __restrict__ Wg,
    const float* __restrict__ bg, float* __restrict__ out_probs,
    float* __restrict__ out_idx, int* __restrict__ cnt, int* __restrict__ list)
{
    const int t = blockIdx.x;
    const int l = threadIdx.x;
    double part[E_NUM];
#pragma unroll
    for (int e = 0; e < E_NUM; e++) part[e] = 0.0;
    const float* xr = x + (size_t)t * D_DIM;
#pragma unroll
    for (int i = 0; i < D_DIM / 64; i++) {
        const int d = l + i * 64;
        const float xv = xr[d];
        const float* wr = Wg + (size_t)d * E_NUM;
        float4 w0 = *(const float4*)(wr);
        float4 w1 = *(const float4*)(wr + 4);
        part[0] += (double)xv * (double)w0.x;
        part[1] += (double)xv * (double)w0.y;
        part[2] += (double)xv * (double)w0.z;
        part[3] += (double)xv * (double)w0.w;
        part[4] += (double)xv * (double)w1.x;
        part[5] += (double)xv * (double)w1.y;
        part[6] += (double)xv * (double)w1.z;
        part[7] += (double)xv * (double)w1.w;
    }
#pragma unroll
    for (int e = 0; e < E_NUM; e++) {
        double v = part[e];
        for (int s = 32; s > 0; s >>= 1) v += __shfl_xor(v, s, 64);
        part[e] = v;
    }
    if (l == 0) {
        float logits[E_NUM], probs[E_NUM];
        float m = -3.0e38f;
#pragma unroll
        for (int e = 0; e < E_NUM; e++) {
            logits[e] = (float)(part[e] + (double)bg[e]);
            m = fmaxf(m, logits[e]);
        }
        float s = 0.f;
#pragma unroll
        for (int e = 0; e < E_NUM; e++) { probs[e] = expf(logits[e] - m); s += probs[e]; }
        const float inv = 1.f / s;
        int best = 0; float bp = -1.f;
#pragma unroll
        for (int e = 0; e < E_NUM; e++) {
            probs[e] *= inv;
            if (probs[e] > bp) { bp = probs[e]; best = e; }
        }
#pragma unroll
        for (int e = 0; e < E_NUM; e++) out_probs[(size_t)t * E_NUM + e] = probs[e];
        out_idx[t] = (float)best;
        const int pos = atomicAdd(&cnt[best], 1);
        list[best * NTOK + pos] = t;
    }
}

__global__ void zero_cnt_kernel(int* cnt)
{
    if (threadIdx.x < E_NUM) cnt[threadIdx.x] = 0;
}

// prefix offsets + compact row-tile table (expert, local row0 of each 256-row tile)
__global__ void offsets_kernel(const int* __restrict__ cnt, int* __restrict__ off,
                               int* __restrict__ tile_e, int* __restrict__ tile_row,
                               int* __restrict__ tile_n)
{
    if (threadIdx.x == 0) {
        int a = 0, n = 0;
        for (int e = 0; e < E_NUM; e++) {
            off[e] = a; a += cnt[e];
            for (int rr = 0; rr < cnt[e]; rr += BM) {
                tile_e[n] = e; tile_row[n] = rr; n++;
            }
        }
        tile_n[0] = n;
    }
}

// gather routed x rows into bf16, contiguous per expert
__global__ __launch_bounds__(256) void gather_kernel(
    const float* __restrict__ x, const int* __restrict__ off,
    const int* __restrict__ cnt, const int* __restrict__ list,
    bf16* __restrict__ Xg)
{
    const int p = blockIdx.x;
    int e = 0;
    while (e < E_NUM - 1 && p >= off[e] + cnt[e]) e++;
    const int token = list[e * NTOK + (p - off[e])];
    const float* src = x + (size_t)token * D_DIM;
    bf16* dst = Xg + (size_t)p * D_DIM;
    const int t = threadIdx.x;
    float4 v = *(const float4*)(src + t * 4);
    bf16x4 o;
    o[0] = (bf16)v.x; o[1] = (bf16)v.y; o[2] = (bf16)v.z; o[3] = (bf16)v.w;
    *(bf16x4*)(dst + t * 4) = o;
}

// transpose+convert one [K][N] fp32 matrix (per expert) to [N][K] bf16. 64x64 tiles.
__global__ __launch_bounds__(256) void transpose_conv_kernel(
    const float* __restrict__ in, bf16* __restrict__ out, int K, int N)
{
    const int e = blockIdx.z;
    const float* src = in + (size_t)e * K * N;
    bf16* dst = out + (size_t)e * K * N;
    __shared__ float T[64][65];
    const int t = threadIdx.x;
    const int k0 = blockIdx.x * 64, n0 = blockIdx.y * 64;
    {
        const int ty = t >> 4;
        const int tx = (t & 15) * 4;
#pragma unroll
        for (int i = 0; i < 4; i++) {
            float4 v = *(const float4*)(src + (size_t)(k0 + ty + 16 * i) * N + n0 + tx);
            T[ty + 16 * i][tx + 0] = v.x; T[ty + 16 * i][tx + 1] = v.y;
            T[ty + 16 * i][tx + 2] = v.z; T[ty + 16 * i][tx + 3] = v.w;
        }
    }
    __syncthreads();
    {
        const int n  = t >> 2;
        const int kx = (t & 3) * 16;
        bf16 tmp[16];
#pragma unroll
        for (int j = 0; j < 16; j++) tmp[j] = (bf16)T[kx + j][n];
        *(bf16x8*)(dst + (size_t)(n0 + n) * K + k0 + kx)     = *(bf16x8*)&tmp[0];
        *(bf16x8*)(dst + (size_t)(n0 + n) * K + k0 + kx + 8) = *(bf16x8*)&tmp[8];
    }
}

// partial sums of c[e][d] = relu(b1[e]) . W2[e][:,d]
__global__ __launch_bounds__(256) void cpart_kernel(
    const float* __restrict__ W2, const float* __restrict__ b1,
    float* __restrict__ cpart)
{
    const int chunk = blockIdx.x;
    const int e = blockIdx.y;
    const int t = threadIdx.x;
    float acc0 = 0.f, acc1 = 0.f, acc2 = 0.f, acc3 = 0.f;
    for (int hh = 0; hh < H_DIM / 32; hh++) {
        const int h = chunk * (H_DIM / 32) + hh;
        const float rb = fmaxf(b1[(size_t)e * H_DIM + h], 0.f);
        float4 w = *(const float4*)(W2 + ((size_t)e * H_DIM + h) * D_DIM + t * 4);
        acc0 += rb * w.x; acc1 += rb * w.y; acc2 += rb * w.z; acc3 += rb * w.w;
    }
    float* dst = cpart + ((size_t)(e * 32 + chunk)) * D_DIM + t * 4;
    dst[0] = acc0; dst[1] = acc1; dst[2] = acc2; dst[3] = acc3;
}

__global__ __launch_bounds__(256) void cfinal_kernel(
    const float* __restrict__ cpart, const float* __restrict__ b2,
    float* __restrict__ adj)
{
    const int d = blockIdx.x * 256 + threadIdx.x;
    float c[E_NUM];
    float tot = 0.f;
#pragma unroll
    for (int e = 0; e < E_NUM; e++) {
        float s = 0.f;
        for (int ch = 0; ch < 32; ch++) s += cpart[((size_t)(e * 32 + ch)) * D_DIM + d];
        s += b2[(size_t)e * D_DIM + d];
        c[e] = s; tot += s;
    }
#pragma unroll
    for (int e = 0; e < E_NUM; e++) adj[(size_t)e * D_DIM + d] = tot - c[e];
}

// ---------------- grouped GEMM 1 (8-phase 256x256): h = relu(Xg @ W1t^T + b1) ----------------
__global__ __launch_bounds__(512, 2) void gemm1_kernel(
    const bf16* __restrict__ Xg, const bf16* __restrict__ W1t,
    const float* __restrict__ b1, const int* __restrict__ cnt,
    const int* __restrict__ off, const int* __restrict__ tile_e,
    const int* __restrict__ tile_row, const int* __restrict__ tile_n,
    bf16* __restrict__ Hb)
{
    const int orig = blockIdx.x;
    const int qch = (MAXT * NBY1) >> 3;        // 640/8 = 80
    const int fid = (orig & 7) * qch + (orig >> 3);
    const int tx = fid % MAXT;
    const int by = fid / MAXT;
    if (tx >= tile_n[0]) return;
    const int e  = tile_e[tx];
    const int m0 = tile_row[tx];
    const int ne = cnt[e];
    const int oe = off[e];
    const int K = D_DIM;

    __shared__ bf16 sA[2][BM * BK];
    __shared__ bf16 sB[2][BN * BK];

    const int t = threadIdx.x;
    const int w = t >> 6, lane = t & 63;
    const int wr = w >> 2, wc = w & 3;         // 2M x 4N waves
    const int l15 = lane & 15, q8 = (lane >> 4) * 8;

    const int srow = t >> 3;                   // 0..63
    const int schk = (t & 7) * 8;              // k-chunk elem offset
    const bf16* Asrc = Xg + (size_t)(oe + m0 + srow) * K + schk;
    const bf16* Bsrc = W1t + ((size_t)e * H_DIM + by * BN + srow) * K + schk;

    f32x4 acc[8][4];
#pragma unroll
    for (int i = 0; i < 8; i++)
#pragma unroll
        for (int j = 0; j < 4; j++) acc[i][j] = (f32x4){0.f, 0.f, 0.f, 0.f};

    KLOOP(K / BK);

    // epilogue: bias + relu -> Hb (bf16)
    float bias[4];
#pragma unroll
    for (int j = 0; j < 4; j++)
        bias[j] = b1[(size_t)e * H_DIM + by * BN + wc * 64 + j * 16 + l15];
#pragma unroll
    for (int i = 0; i < 8; i++) {
        const int rb0 = m0 + i * 32 + wr * 16 + ((lane >> 4) << 2);
#pragma unroll
        for (int j = 0; j < 4; j++) {
            const int gcol = by * BN + wc * 64 + j * 16 + l15;
#pragma unroll
            for (int r = 0; r < 4; r++) {
                const int grow = rb0 + r;
                if (grow < ne) {
                    float v = acc[i][j][r] + bias[j];
                    Hb[((size_t)(oe + grow)) * H_DIM + gcol] = (bf16)fmaxf(v, 0.f);
                }
            }
        }
    }
}

// ---------------- grouped GEMM 2 (8-phase 256x256): out = h @ W2t^T + b2 + adj ----------------
__global__ __launch_bounds__(512, 2) void gemm2_kernel(
    const bf16* __restrict__ Hb, const bf16* __restrict__ W2t,
    const float* __restrict__ b2, const float* __restrict__ adj,
    const int* __restrict__ cnt, const int* __restrict__ off,
    const int* __restrict__ tile_e, const int* __restrict__ tile_row,
    const int* __restrict__ tile_n, const int* __restrict__ list,
    float* __restrict__ out)
{
    const int orig = blockIdx.x;
    const int qch = (MAXT * NBY2) >> 3;        // 160/8 = 20
    const int fid = (orig & 7) * qch + (orig >> 3);
    const int tx = fid % MAXT;
    const int by = fid / MAXT;
    if (tx >= tile_n[0]) return;
    const int e  = tile_e[tx];
    const int m0 = tile_row[tx];
    const int ne = cnt[e];
    const int oe = off[e];
    const int K = H_DIM;

    __shared__ bf16 sA[2][BM * BK];
    __shared__ bf16 sB[2][BN * BK];

    const int t = threadIdx.x;
    const int w = t >> 6, lane = t & 63;
    const int wr = w >> 2, wc = w & 3;
    const int l15 = lane & 15, q8 = (lane >> 4) * 8;

    const int srow = t >> 3;
    const int schk = (t & 7) * 8;
    const bf16* Asrc = Hb + (size_t)(oe + m0 + srow) * K + schk;
    const bf16* Bsrc = W2t + ((size_t)e * D_DIM + by * BN + srow) * K + schk;

    f32x4 acc[8][4];
#pragma unroll
    for (int i = 0; i < 8; i++)
#pragma unroll
        for (int j = 0; j < 4; j++) acc[i][j] = (f32x4){0.f, 0.f, 0.f, 0.f};

    KLOOP(K / BK);

    float badj[4];
#pragma unroll
    for (int j = 0; j < 4; j++) {
        const int gcol = by * BN + wc * 64 + j * 16 + l15;
        badj[j] = b2[(size_t)e * D_DIM + gcol] + adj[(size_t)e * D_DIM + gcol];
    }
#pragma unroll
    for (int i = 0; i < 8; i++) {
        const int rb0 = m0 + i * 32 + wr * 16 + ((lane >> 4) << 2);
#pragma unroll
        for (int j = 0; j < 4; j++) {
            const int gcol = by * BN + wc * 64 + j * 16 + l15;
#pragma unroll
            for (int r = 0; r < 4; r++) {
                const int grow = rb0 + r;
                if (grow < ne) {
                    const int tok = list[e * NTOK + grow];
                    out[(size_t)tok * D_DIM + gcol] = acc[i][j][r] + badj[j];
                }
            }
        }
    }
}

extern "C" void kernel_launch(void* const* d_in, const int* in_sizes, int n_in,
                              void* d_out, int out_size, void* d_ws, size_t ws_size,
                              hipStream_t stream)
{
    (void)in_sizes; (void)n_in; (void)out_size; (void)ws_size;
    const float* x  = (const float*)d_in[0];
    const float* Wg = (const float*)d_in[1];
    const float* bg = (const float*)d_in[2];
    const float* W1 = (const float*)d_in[3];
    const float* b1 = (const float*)d_in[4];
    const float* W2 = (const float*)d_in[5];
    const float* b2 = (const float*)d_in[6];

    float* out_comb  = (float*)d_out;
    float* out_probs = out_comb + (size_t)NTOK * D_DIM;
    float* out_idx   = out_probs + (size_t)NTOK * E_NUM;

    // ws layout: GEMM A-staging can overread up to 255 rows past the end of
    // Xg (510 KB) and Hb (2 MB) — Xg is followed by cpart+adj+lists (>1.3 MB)
    // and Hb by Xg (16 MB), so all overshoot stays inside d_ws (values unused:
    // rows >= ne are never written out).
    char* ws = (char*)d_ws;
    size_t o = 0;
    bf16* W1t = (bf16*)(ws + o); o += (size_t)E_NUM * H_DIM * D_DIM * 2;  // 64MB
    bf16* W2t = (bf16*)(ws + o); o += (size_t)E_NUM * H_DIM * D_DIM * 2;  // 64MB
    bf16* Hb  = (bf16*)(ws + o); o += (size_t)NTOK * H_DIM * 2;           // 64MB
    bf16* Xg  = (bf16*)(ws + o); o += (size_t)NTOK * D_DIM * 2;           // 16MB
    float* cpart = (float*)(ws + o); o += (size_t)E_NUM * 32 * D_DIM * 4; // 1MB
    float* adj   = (float*)(ws + o); o += (size_t)E_NUM * D_DIM * 4;      // 32KB
    int* cnt  = (int*)(ws + o); o += 256;
    int* off  = (int*)(ws + o); o += 256;
    int* tile_e   = (int*)(ws + o); o += 512;
    int* tile_row = (int*)(ws + o); o += 512;
    int* tile_n   = (int*)(ws + o); o += 256;
    int* list = (int*)(ws + o); o += (size_t)E_NUM * NTOK * 4;            // 256KB

    zero_cnt_kernel<<<1, 64, 0, stream>>>(cnt);
    gate_kernel<<<NTOK, 64, 0, stream>>>(x, Wg, bg, out_probs, out_idx, cnt, list);
    offsets_kernel<<<1, 64, 0, stream>>>(cnt, off, tile_e, tile_row, tile_n);
    gather_kernel<<<NTOK, 256, 0, stream>>>(x, off, cnt, list, Xg);
    transpose_conv_kernel<<<dim3(D_DIM / 64, H_DIM / 64, E_NUM), 256, 0, stream>>>(W1, W1t, D_DIM, H_DIM);
    transpose_conv_kernel<<<dim3(H_DIM / 64, D_DIM / 64, E_NUM), 256, 0, stream>>>(W2, W2t, H_DIM, D_DIM);
    cpart_kernel<<<dim3(32, E_NUM), 256, 0, stream>>>(W2, b1, cpart);
    cfinal_kernel<<<D_DIM / 256, 256, 0, stream>>>(cpart, b2, adj);
    gemm1_kernel<<<MAXT * NBY1, 512, 0, stream>>>(Xg, W1t, b1, cnt, off, tile_e, tile_row, tile_n, Hb);
    gemm2_kernel<<<MAXT * NBY2, 512, 0, stream>>>(Hb, W2t, b2, adj, cnt, off, tile_e, tile_row, tile_n, list, out_comb);
}

// Round 5
// 701.719 us; speedup vs baseline: 1.0412x; 1.0412x over previous
//
#include <hip/hip_runtime.h>
#include <hip/hip_bf16.h>
#include <cstdint>

#define D_DIM 1024
#define H_DIM 4096
#define E_NUM 8
#define NTOK  8192

#define BM 256
#define BN 256
#define BK 64

#define MAXT 40             // worst-case row-tiles: sum ceil(ne/256) <= 39
#define NBY1 (H_DIM / BN)   // 16
#define NBY2 (D_DIM / BN)   // 4

typedef __bf16 bf16;
typedef __bf16 bf16x8 __attribute__((ext_vector_type(8)));
typedef __bf16 bf16x4 __attribute__((ext_vector_type(4)));
typedef float  f32x4  __attribute__((ext_vector_type(4)));

// global_load_lds: per-lane global src, wave-uniform LDS base + lane*16B dest
#define GLOAD16(g, l)                                                          \
    __builtin_amdgcn_global_load_lds(                                          \
        (const __attribute__((address_space(1))) void*)(g),                    \
        (__attribute__((address_space(3))) void*)(l), 16, 0, 0)

// ---- 8-phase GEMM building blocks (shared by gemm1/gemm2 via macros) ----
// LDS tiles sA/sB: [2 bufs][256 rows][64 k] bf16.
// T2 XOR-swizzle (both-sides involution, rule #21):
//   stored(row, chunk) holds logical (row, chunk ^ (row&7)), chunk = 16B unit.
//   - write side: LDS dest stays LINEAR (global_load_lds requirement); the
//     per-lane GLOBAL source column is pre-swizzled: chunk_src = (t&7)^((t>>3)&7)
//   - read side: fragment reads XOR the chunk with row&7 (row&7 == lane&7)
// Half-tiles by row (lo = rows 0-127, hi = 128-255), staged one per phase.
#define STAGE_A(bf, h, tt) do {                                                \
    GLOAD16(Asrc + (size_t)((h) * 128) * K + (size_t)(tt) * BK,                \
            &sA[(bf)][((h) * 128 + (w << 3)) * BK]);                           \
    GLOAD16(Asrc + (size_t)((h) * 128 + 64) * K + (size_t)(tt) * BK,           \
            &sA[(bf)][((h) * 128 + 64 + (w << 3)) * BK]);                      \
} while (0)
#define STAGE_B(bf, h, tt) do {                                                \
    GLOAD16(Bsrc + (size_t)((h) * 128) * K + (size_t)(tt) * BK,                \
            &sB[(bf)][((h) * 128 + (w << 3)) * BK]);                           \
    GLOAD16(Bsrc + (size_t)((h) * 128 + 64) * K + (size_t)(tt) * BK,           \
            &sB[(bf)][((h) * 128 + 64 + (w << 3)) * BK]);                      \
} while (0)

// fragment loads: A row = i*32 + wr*16 + l15; B row = wc*64 + j*16 + l15
// swizzled k-offset: kidx0/kidx1 precomputed per thread (kh is a literal)
#define LDA(i, kh) (*(const bf16x8*)&sA[buf][((i) * 32 + wr * 16 + l15) * BK + ((kh) ? kidx1 : kidx0)])
#define LDB(j, kh) (*(const bf16x8*)&sB[buf][(wc * 64 + (j) * 16 + l15) * BK + ((kh) ? kidx1 : kidx0)])

#define MM4(I, AA, B0, B1, B2, B3) do {                                        \
    acc[I][0] = __builtin_amdgcn_mfma_f32_16x16x32_bf16(AA, B0, acc[I][0], 0, 0, 0); \
    acc[I][1] = __builtin_amdgcn_mfma_f32_16x16x32_bf16(AA, B1, acc[I][1], 0, 0, 0); \
    acc[I][2] = __builtin_amdgcn_mfma_f32_16x16x32_bf16(AA, B2, acc[I][2], 0, 0, 0); \
    acc[I][3] = __builtin_amdgcn_mfma_f32_16x16x32_bf16(AA, B3, acc[I][3], 0, 0, 0); \
} while (0)

#define VMCNT2() asm volatile("s_waitcnt vmcnt(2)" ::: "memory")

// K-loop: 4 phases/tile. Stage order: ph1 A-hi(t+1), ph2 B-lo(t+1),
// ph3 B-hi(t+1), ph4 A-lo(t+2). Single vmcnt(2) at end-ph4 guarantees
// tile t+1's 4 half-tiles landed before its reads, while A-lo(t+2) stays
// in flight across the barrier (never drain to 0).
#define KLOOP(NT) do {                                                         \
    STAGE_A(0, 0, 0); STAGE_B(0, 0, 0); STAGE_B(0, 1, 0); STAGE_A(0, 1, 0);    \
    STAGE_A(1, 0, 1);                                                          \
    VMCNT2();                                                                  \
    __syncthreads();                                                           \
    for (int kt = 0; kt < (NT); kt++) {                                        \
        const int buf = kt & 1, ob = buf ^ 1;                                  \
        const int tp1 = (kt + 1 < (NT)) ? kt + 1 : 0;                          \
        const int tp2 = (kt + 2 < (NT)) ? kt + 2 : kt + 2 - (NT);              \
        bf16x8 a0, a1, a2, a3, bb0, bb1, bb2, bb3, cc0, cc1, cc2, cc3;         \
        /* ph1: m-frags 0-3, k-half 0 */                                       \
        a0 = LDA(0, 0); a1 = LDA(1, 0); a2 = LDA(2, 0); a3 = LDA(3, 0);        \
        bb0 = LDB(0, 0); bb1 = LDB(1, 0); bb2 = LDB(2, 0); bb3 = LDB(3, 0);    \
        STAGE_A(ob, 1, tp1);                                                   \
        __syncthreads();                                                       \
        __builtin_amdgcn_s_setprio(1);                                         \
        MM4(0, a0, bb0, bb1, bb2, bb3); MM4(1, a1, bb0, bb1, bb2, bb3);        \
        MM4(2, a2, bb0, bb1, bb2, bb3); MM4(3, a3, bb0, bb1, bb2, bb3);        \
        __builtin_amdgcn_s_setprio(0);                                         \
        __syncthreads();                                                       \
        /* ph2: m-frags 4-7, k-half 0 (B regs reused) */                       \
        a0 = LDA(4, 0); a1 = LDA(5, 0); a2 = LDA(6, 0); a3 = LDA(7, 0);        \
        STAGE_B(ob, 0, tp1);                                                   \
        __syncthreads();                                                       \
        __builtin_amdgcn_s_setprio(1);                                         \
        MM4(4, a0, bb0, bb1, bb2, bb3); MM4(5, a1, bb0, bb1, bb2, bb3);        \
        MM4(6, a2, bb0, bb1, bb2, bb3); MM4(7, a3, bb0, bb1, bb2, bb3);        \
        __builtin_amdgcn_s_setprio(0);                                         \
        __syncthreads();                                                       \
        /* ph3: m-frags 0-3, k-half 1 */                                       \
        a0 = LDA(0, 1); a1 = LDA(1, 1); a2 = LDA(2, 1); a3 = LDA(3, 1);        \
        cc0 = LDB(0, 1); cc1 = LDB(1, 1); cc2 = LDB(2, 1); cc3 = LDB(3, 1);    \
        STAGE_B(ob, 1, tp1);                                                   \
        __syncthreads();                                                       \
        __builtin_amdgcn_s_setprio(1);                                         \
        MM4(0, a0, cc0, cc1, cc2, cc3); MM4(1, a1, cc0, cc1, cc2, cc3);        \
        MM4(2, a2, cc0, cc1, cc2, cc3); MM4(3, a3, cc0, cc1, cc2, cc3);        \
        __builtin_amdgcn_s_setprio(0);                                         \
        __syncthreads();                                                       \
        /* ph4: m-frags 4-7, k-half 1 */                                       \
        a0 = LDA(4, 1); a1 = LDA(5, 1); a2 = LDA(6, 1); a3 = LDA(7, 1);        \
        STAGE_A(buf, 0, tp2);                                                  \
        __syncthreads();                                                       \
        __builtin_amdgcn_s_setprio(1);                                         \
        MM4(4, a0, cc0, cc1, cc2, cc3); MM4(5, a1, cc0, cc1, cc2, cc3);        \
        MM4(6, a2, cc0, cc1, cc2, cc3); MM4(7, a3, cc0, cc1, cc2, cc3);        \
        __builtin_amdgcn_s_setprio(0);                                         \
        VMCNT2();                                                              \
        __syncthreads();                                                       \
    }                                                                          \
} while (0)

// ---------------- gating ----------------
__global__ __launch_bounds__(64) void gate_kernel(
    const float* __restrict__ x, const float* __restrict__ Wg,
    const float* __restrict__ bg, float* __restrict__ out_probs,
    float* __restrict__ out_idx, int* __restrict__ cnt, int* __restrict__ list)
{
    const int t = blockIdx.x;
    const int l = threadIdx.x;
    double part[E_NUM];
#pragma unroll
    for (int e = 0; e < E_NUM; e++) part[e] = 0.0;
    const float* xr = x + (size_t)t * D_DIM;
#pragma unroll
    for (int i = 0; i < D_DIM / 64; i++) {
        const int d = l + i * 64;
        const float xv = xr[d];
        const float* wr = Wg + (size_t)d * E_NUM;
        float4 w0 = *(const float4*)(wr);
        float4 w1 = *(const float4*)(wr + 4);
        part[0] += (double)xv * (double)w0.x;
        part[1] += (double)xv * (double)w0.y;
        part[2] += (double)xv * (double)w0.z;
        part[3] += (double)xv * (double)w0.w;
        part[4] += (double)xv * (double)w1.x;
        part[5] += (double)xv * (double)w1.y;
        part[6] += (double)xv * (double)w1.z;
        part[7] += (double)xv * (double)w1.w;
    }
#pragma unroll
    for (int e = 0; e < E_NUM; e++) {
        double v = part[e];
        for (int s = 32; s > 0; s >>= 1) v += __shfl_xor(v, s, 64);
        part[e] = v;
    }
    if (l == 0) {
        float logits[E_NUM], probs[E_NUM];
        float m = -3.0e38f;
#pragma unroll
        for (int e = 0; e < E_NUM; e++) {
            logits[e] = (float)(part[e] + (double)bg[e]);
            m = fmaxf(m, logits[e]);
        }
        float s = 0.f;
#pragma unroll
        for (int e = 0; e < E_NUM; e++) { probs[e] = expf(logits[e] - m); s += probs[e]; }
        const float inv = 1.f / s;
        int best = 0; float bp = -1.f;
#pragma unroll
        for (int e = 0; e < E_NUM; e++) {
            probs[e] *= inv;
            if (probs[e] > bp) { bp = probs[e]; best = e; }
        }
#pragma unroll
        for (int e = 0; e < E_NUM; e++) out_probs[(size_t)t * E_NUM + e] = probs[e];
        out_idx[t] = (float)best;
        const int pos = atomicAdd(&cnt[best], 1);
        list[best * NTOK + pos] = t;
    }
}

__global__ void zero_cnt_kernel(int* cnt)
{
    if (threadIdx.x < E_NUM) cnt[threadIdx.x] = 0;
}

// prefix offsets + compact row-tile table (expert, local row0 of each 256-row tile)
__global__ void offsets_kernel(const int* __restrict__ cnt, int* __restrict__ off,
                               int* __restrict__ tile_e, int* __restrict__ tile_row,
                               int* __restrict__ tile_n)
{
    if (threadIdx.x == 0) {
        int a = 0, n = 0;
        for (int e = 0; e < E_NUM; e++) {
            off[e] = a; a += cnt[e];
            for (int rr = 0; rr < cnt[e]; rr += BM) {
                tile_e[n] = e; tile_row[n] = rr; n++;
            }
        }
        tile_n[0] = n;
    }
}

// gather routed x rows into bf16, contiguous per expert
__global__ __launch_bounds__(256) void gather_kernel(
    const float* __restrict__ x, const int* __restrict__ off,
    const int* __restrict__ cnt, const int* __restrict__ list,
    bf16* __restrict__ Xg)
{
    const int p = blockIdx.x;
    int e = 0;
    while (e < E_NUM - 1 && p >= off[e] + cnt[e]) e++;
    const int token = list[e * NTOK + (p - off[e])];
    const float* src = x + (size_t)token * D_DIM;
    bf16* dst = Xg + (size_t)p * D_DIM;
    const int t = threadIdx.x;
    float4 v = *(const float4*)(src + t * 4);
    bf16x4 o;
    o[0] = (bf16)v.x; o[1] = (bf16)v.y; o[2] = (bf16)v.z; o[3] = (bf16)v.w;
    *(bf16x4*)(dst + t * 4) = o;
}

// transpose+convert one [K][N] fp32 matrix (per expert) to [N][K] bf16. 64x64 tiles.
__global__ __launch_bounds__(256) void transpose_conv_kernel(
    const float* __restrict__ in, bf16* __restrict__ out, int K, int N)
{
    const int e = blockIdx.z;
    const float* src = in + (size_t)e * K * N;
    bf16* dst = out + (size_t)e * K * N;
    __shared__ float T[64][65];
    const int t = threadIdx.x;
    const int k0 = blockIdx.x * 64, n0 = blockIdx.y * 64;
    {
        const int ty = t >> 4;
        const int tx = (t & 15) * 4;
#pragma unroll
        for (int i = 0; i < 4; i++) {
            float4 v = *(const float4*)(src + (size_t)(k0 + ty + 16 * i) * N + n0 + tx);
            T[ty + 16 * i][tx + 0] = v.x; T[ty + 16 * i][tx + 1] = v.y;
            T[ty + 16 * i][tx + 2] = v.z; T[ty + 16 * i][tx + 3] = v.w;
        }
    }
    __syncthreads();
    {
        const int n  = t >> 2;
        const int kx = (t & 3) * 16;
        bf16 tmp[16];
#pragma unroll
        for (int j = 0; j < 16; j++) tmp[j] = (bf16)T[kx + j][n];
        *(bf16x8*)(dst + (size_t)(n0 + n) * K + k0 + kx)     = *(bf16x8*)&tmp[0];
        *(bf16x8*)(dst + (size_t)(n0 + n) * K + k0 + kx + 8) = *(bf16x8*)&tmp[8];
    }
}

// partial sums of c[e][d] = relu(b1[e]) . W2[e][:,d]
__global__ __launch_bounds__(256) void cpart_kernel(
    const float* __restrict__ W2, const float* __restrict__ b1,
    float* __restrict__ cpart)
{
    const int chunk = blockIdx.x;
    const int e = blockIdx.y;
    const int t = threadIdx.x;
    float acc0 = 0.f, acc1 = 0.f, acc2 = 0.f, acc3 = 0.f;
    for (int hh = 0; hh < H_DIM / 32; hh++) {
        const int h = chunk * (H_DIM / 32) + hh;
        const float rb = fmaxf(b1[(size_t)e * H_DIM + h], 0.f);
        float4 w = *(const float4*)(W2 + ((size_t)e * H_DIM + h) * D_DIM + t * 4);
        acc0 += rb * w.x; acc1 += rb * w.y; acc2 += rb * w.z; acc3 += rb * w.w;
    }
    float* dst = cpart + ((size_t)(e * 32 + chunk)) * D_DIM + t * 4;
    dst[0] = acc0; dst[1] = acc1; dst[2] = acc2; dst[3] = acc3;
}

__global__ __launch_bounds__(256) void cfinal_kernel(
    const float* __restrict__ cpart, const float* __restrict__ b2,
    float* __restrict__ adj)
{
    const int d = blockIdx.x * 256 + threadIdx.x;
    float c[E_NUM];
    float tot = 0.f;
#pragma unroll
    for (int e = 0; e < E_NUM; e++) {
        float s = 0.f;
        for (int ch = 0; ch < 32; ch++) s += cpart[((size_t)(e * 32 + ch)) * D_DIM + d];
        s += b2[(size_t)e * D_DIM + d];
        c[e] = s; tot += s;
    }
#pragma unroll
    for (int e = 0; e < E_NUM; e++) adj[(size_t)e * D_DIM + d] = tot - c[e];
}

// ---------------- grouped GEMM 1 (8-phase 256x256 + T2 swizzle): h = relu(Xg @ W1t^T + b1) ----------------
__global__ __launch_bounds__(512, 2) void gemm1_kernel(
    const bf16* __restrict__ Xg, const bf16* __restrict__ W1t,
    const float* __restrict__ b1, const int* __restrict__ cnt,
    const int* __restrict__ off, const int* __restrict__ tile_e,
    const int* __restrict__ tile_row, const int* __restrict__ tile_n,
    bf16* __restrict__ Hb)
{
    const int orig = blockIdx.x;
    const int qch = (MAXT * NBY1) >> 3;        // 640/8 = 80
    const int fid = (orig & 7) * qch + (orig >> 3);
    const int tx = fid % MAXT;
    const int by = fid / MAXT;
    if (tx >= tile_n[0]) return;
    const int e  = tile_e[tx];
    const int m0 = tile_row[tx];
    const int ne = cnt[e];
    const int oe = off[e];
    const int K = D_DIM;

    __shared__ bf16 sA[2][BM * BK];
    __shared__ bf16 sB[2][BN * BK];

    const int t = threadIdx.x;
    const int w = t >> 6, lane = t & 63;
    const int wr = w >> 2, wc = w & 3;         // 2M x 4N waves
    const int l15 = lane & 15;
    // T2 read-side swizzle: chunk' = (kh*4 + lane>>4) ^ (lane&7), elems = chunk'*8
    const int kidx0 = (((lane >> 4)) ^ (lane & 7)) << 3;
    const int kidx1 = ((4 + (lane >> 4)) ^ (lane & 7)) << 3;

    const int srow = t >> 3;                   // 0..63
    // T2 write-side: pre-swizzled GLOBAL source chunk (LDS dest stays linear)
    const int schk = (((t & 7) ^ ((t >> 3) & 7)) << 3);
    const bf16* Asrc = Xg + (size_t)(oe + m0 + srow) * K + schk;
    const bf16* Bsrc = W1t + ((size_t)e * H_DIM + by * BN + srow) * K + schk;

    f32x4 acc[8][4];
#pragma unroll
    for (int i = 0; i < 8; i++)
#pragma unroll
        for (int j = 0; j < 4; j++) acc[i][j] = (f32x4){0.f, 0.f, 0.f, 0.f};

    KLOOP(K / BK);

    // epilogue: bias + relu -> Hb (bf16)
    float bias[4];
#pragma unroll
    for (int j = 0; j < 4; j++)
        bias[j] = b1[(size_t)e * H_DIM + by * BN + wc * 64 + j * 16 + l15];
#pragma unroll
    for (int i = 0; i < 8; i++) {
        const int rb0 = m0 + i * 32 + wr * 16 + ((lane >> 4) << 2);
#pragma unroll
        for (int j = 0; j < 4; j++) {
            const int gcol = by * BN + wc * 64 + j * 16 + l15;
#pragma unroll
            for (int r = 0; r < 4; r++) {
                const int grow = rb0 + r;
                if (grow < ne) {
                    float v = acc[i][j][r] + bias[j];
                    Hb[((size_t)(oe + grow)) * H_DIM + gcol] = (bf16)fmaxf(v, 0.f);
                }
            }
        }
    }
}

// ---------------- grouped GEMM 2 (8-phase 256x256 + T2 swizzle): out = h @ W2t^T + b2 + adj ----------------
__global__ __launch_bounds__(512, 2) void gemm2_kernel(
    const bf16* __restrict__ Hb, const bf16* __restrict__ W2t,
    const float* __restrict__ b2, const float* __restrict__ adj,
    const int* __restrict__ cnt, const int* __restrict__ off,
    const int* __restrict__ tile_e, const int* __restrict__ tile_row,
    const int* __restrict__ tile_n, const int* __restrict__ list,
    float* __restrict__ out)
{
    const int orig = blockIdx.x;
    const int qch = (MAXT * NBY2) >> 3;        // 160/8 = 20
    const int fid = (orig & 7) * qch + (orig >> 3);
    const int tx = fid % MAXT;
    const int by = fid / MAXT;
    if (tx >= tile_n[0]) return;
    const int e  = tile_e[tx];
    const int m0 = tile_row[tx];
    const int ne = cnt[e];
    const int oe = off[e];
    const int K = H_DIM;

    __shared__ bf16 sA[2][BM * BK];
    __shared__ bf16 sB[2][BN * BK];

    const int t = threadIdx.x;
    const int w = t >> 6, lane = t & 63;
    const int wr = w >> 2, wc = w & 3;
    const int l15 = lane & 15;
    const int kidx0 = (((lane >> 4)) ^ (lane & 7)) << 3;
    const int kidx1 = ((4 + (lane >> 4)) ^ (lane & 7)) << 3;

    const int srow = t >> 3;
    const int schk = (((t & 7) ^ ((t >> 3) & 7)) << 3);
    const bf16* Asrc = Hb + (size_t)(oe + m0 + srow) * K + schk;
    const bf16* Bsrc = W2t + ((size_t)e * D_DIM + by * BN + srow) * K + schk;

    f32x4 acc[8][4];
#pragma unroll
    for (int i = 0; i < 8; i++)
#pragma unroll
        for (int j = 0; j < 4; j++) acc[i][j] = (f32x4){0.f, 0.f, 0.f, 0.f};

    KLOOP(K / BK);

    float badj[4];
#pragma unroll
    for (int j = 0; j < 4; j++) {
        const int gcol = by * BN + wc * 64 + j * 16 + l15;
        badj[j] = b2[(size_t)e * D_DIM + gcol] + adj[(size_t)e * D_DIM + gcol];
    }
#pragma unroll
    for (int i = 0; i < 8; i++) {
        const int rb0 = m0 + i * 32 + wr * 16 + ((lane >> 4) << 2);
#pragma unroll
        for (int j = 0; j < 4; j++) {
            const int gcol = by * BN + wc * 64 + j * 16 + l15;
#pragma unroll
            for (int r = 0; r < 4; r++) {
                const int grow = rb0 + r;
                if (grow < ne) {
                    const int tok = list[e * NTOK + grow];
                    out[(size_t)tok * D_DIM + gcol] = acc[i][j][r] + badj[j];
                }
            }
        }
    }
}

extern "C" void kernel_launch(void* const* d_in, const int* in_sizes, int n_in,
                              void* d_out, int out_size, void* d_ws, size_t ws_size,
                              hipStream_t stream)
{
    (void)in_sizes; (void)n_in; (void)out_size; (void)ws_size;
    const float* x  = (const float*)d_in[0];
    const float* Wg = (const float*)d_in[1];
    const float* bg = (const float*)d_in[2];
    const float* W1 = (const float*)d_in[3];
    const float* b1 = (const float*)d_in[4];
    const float* W2 = (const float*)d_in[5];
    const float* b2 = (const float*)d_in[6];

    float* out_comb  = (float*)d_out;
    float* out_probs = out_comb + (size_t)NTOK * D_DIM;
    float* out_idx   = out_probs + (size_t)NTOK * E_NUM;

    // ws layout: GEMM A-staging can overread up to 255 rows past the end of
    // Xg (510 KB) and Hb (2 MB) — Xg is followed by cpart+adj+lists (>1.3 MB)
    // and Hb by Xg (16 MB), so all overshoot stays inside d_ws (values unused:
    // rows >= ne are never written out).
    char* ws = (char*)d_ws;
    size_t o = 0;
    bf16* W1t = (bf16*)(ws + o); o += (size_t)E_NUM * H_DIM * D_DIM * 2;  // 64MB
    bf16* W2t = (bf16*)(ws + o); o += (size_t)E_NUM * H_DIM * D_DIM * 2;  // 64MB
    bf16* Hb  = (bf16*)(ws + o); o += (size_t)NTOK * H_DIM * 2;           // 64MB
    bf16* Xg  = (bf16*)(ws + o); o += (size_t)NTOK * D_DIM * 2;           // 16MB
    float* cpart = (float*)(ws + o); o += (size_t)E_NUM * 32 * D_DIM * 4; // 1MB
    float* adj   = (float*)(ws + o); o += (size_t)E_NUM * D_DIM * 4;      // 32KB
    int* cnt  = (int*)(ws + o); o += 256;
    int* off  = (int*)(ws + o); o += 256;
    int* tile_e   = (int*)(ws + o); o += 512;
    int* tile_row = (int*)(ws + o); o += 512;
    int* tile_n   = (int*)(ws + o); o += 256;
    int* list = (int*)(ws + o); o += (size_t)E_NUM * NTOK * 4;            // 256KB

    zero_cnt_kernel<<<1, 64, 0, stream>>>(cnt);
    gate_kernel<<<NTOK, 64, 0, stream>>>(x, Wg, bg, out_probs, out_idx, cnt, list);
    offsets_kernel<<<1, 64, 0, stream>>>(cnt, off, tile_e, tile_row, tile_n);
    gather_kernel<<<NTOK, 256, 0, stream>>>(x, off, cnt, list, Xg);
    transpose_conv_kernel<<<dim3(D_DIM / 64, H_DIM / 64, E_NUM), 256, 0, stream>>>(W1, W1t, D_DIM, H_DIM);
    transpose_conv_kernel<<<dim3(H_DIM / 64, D_DIM / 64, E_NUM), 256, 0, stream>>>(W2, W2t, H_DIM, D_DIM);
    cpart_kernel<<<dim3(32, E_NUM), 256, 0, stream>>>(W2, b1, cpart);
    cfinal_kernel<<<D_DIM / 256, 256, 0, stream>>>(cpart, b2, adj);
    gemm1_kernel<<<MAXT * NBY1, 512, 0, stream>>>(Xg, W1t, b1, cnt, off, tile_e, tile_row, tile_n, Hb);
    gemm2_kernel<<<MAXT * NBY2, 512, 0, stream>>>(Hb, W2t, b2, adj, cnt, off, tile_e, tile_row, tile_n, list, out_comb);
}

// Round 6
// 560.033 us; speedup vs baseline: 1.3046x; 1.2530x over previous
//
#include <hip/hip_runtime.h>
#include <hip/hip_bf16.h>
#include <cstdint>

#define D_DIM 1024
#define H_DIM 4096
#define E_NUM 8
#define NTOK  8192

#define BM 256
#define BN 256
#define BK 64

#define MAXT 40             // worst-case row-tiles: sum ceil(ne/256) <= 39
#define NBY1 (H_DIM / BN)   // 16
#define NBY2 (D_DIM / BN)   // 4

typedef __bf16 bf16;
typedef __bf16 bf16x8 __attribute__((ext_vector_type(8)));
typedef __bf16 bf16x4 __attribute__((ext_vector_type(4)));
typedef float  f32x4  __attribute__((ext_vector_type(4)));

// global_load_lds: per-lane global src, wave-uniform LDS base + lane*16B dest
#define GLOAD16(g, l)                                                          \
    __builtin_amdgcn_global_load_lds(                                          \
        (const __attribute__((address_space(1))) void*)(g),                    \
        (__attribute__((address_space(3))) void*)(l), 16, 0, 0)

// Raw barrier: compiler-level memory ordering only — does NOT emit the
// s_waitcnt vmcnt(0) drain that __syncthreads() forces before s_barrier.
// That drain was killing the pipeline (every counted vmcnt became moot).
#define SBAR()   asm volatile("s_barrier" ::: "memory")
#define VMCNT4() asm volatile("s_waitcnt vmcnt(4)" ::: "memory")
#define VMCNT0() asm volatile("s_waitcnt vmcnt(0)" ::: "memory")

// ---- 8-phase GEMM building blocks (shared by gemm1/gemm2 via macros) ----
// LDS tiles sA/sB: [2 bufs][256 rows][64 k] bf16.
// T2 XOR-swizzle (both-sides involution): stored(row, chunk) holds logical
// (row, chunk ^ (row&7)); write side pre-swizzles the GLOBAL source chunk
// (LDS dest stays linear for global_load_lds); read side XORs with row&7.
#define STAGE_A(bf, h, tt) do {                                                \
    GLOAD16(Asrc + (size_t)((h) * 128) * K + (size_t)(tt) * BK,                \
            &sA[(bf)][((h) * 128 + (w << 3)) * BK]);                           \
    GLOAD16(Asrc + (size_t)((h) * 128 + 64) * K + (size_t)(tt) * BK,           \
            &sA[(bf)][((h) * 128 + 64 + (w << 3)) * BK]);                      \
} while (0)
#define STAGE_B(bf, h, tt) do {                                                \
    GLOAD16(Bsrc + (size_t)((h) * 128) * K + (size_t)(tt) * BK,                \
            &sB[(bf)][((h) * 128 + (w << 3)) * BK]);                           \
    GLOAD16(Bsrc + (size_t)((h) * 128 + 64) * K + (size_t)(tt) * BK,           \
            &sB[(bf)][((h) * 128 + 64 + (w << 3)) * BK]);                      \
} while (0)

// fragment loads: A row = i*32 + wr*16 + l15; B row = wc*64 + j*16 + l15
#define LDA(i, kh) (*(const bf16x8*)&sA[buf][((i) * 32 + wr * 16 + l15) * BK + ((kh) ? kidx1 : kidx0)])
#define LDB(j, kh) (*(const bf16x8*)&sB[buf][(wc * 64 + (j) * 16 + l15) * BK + ((kh) ? kidx1 : kidx0)])

#define MM4(I, AA, B0, B1, B2, B3) do {                                        \
    acc[I][0] = __builtin_amdgcn_mfma_f32_16x16x32_bf16(AA, B0, acc[I][0], 0, 0, 0); \
    acc[I][1] = __builtin_amdgcn_mfma_f32_16x16x32_bf16(AA, B1, acc[I][1], 0, 0, 0); \
    acc[I][2] = __builtin_amdgcn_mfma_f32_16x16x32_bf16(AA, B2, acc[I][2], 0, 0, 0); \
    acc[I][3] = __builtin_amdgcn_mfma_f32_16x16x32_bf16(AA, B3, acc[I][3], 0, 0, 0); \
} while (0)

// K-loop, 4 phases/tile, counted-vmcnt pipeline (per-load FIFO ledger):
//   invariant entering tile t: outstanding = {A-hi(t), A-lo(t+1)} (4 loads),
//   everything older landed.
//   ph1: read rows0-127/k0, stage B-lo(t+1), VMCNT4 (-> A-hi(t) landed), SBAR, MFMA, SBAR
//   ph2: read rows128-255/k0, stage B-hi(t+1), SBAR, MFMA, SBAR
//   ph3: read rows0-127/k1,  stage A-hi(t+1), SBAR, MFMA, SBAR
//   ph4: read rows128-255/k1, stage A-lo(t+2) into buf (rows 0-127, not read
//        in ph4 — legal), VMCNT4 (-> A-lo/B-lo/B-hi(t+1) landed), SBAR, MFMA, SBAR
// Min slack 2 phases; A half-tiles get 4-5 phases. Never drains to 0 in-loop.
#define KLOOP(NT) do {                                                         \
    STAGE_B(0, 0, 0); STAGE_B(0, 1, 0); STAGE_A(0, 0, 0); STAGE_A(0, 1, 0);    \
    STAGE_A(1, 0, 1);                                                          \
    VMCNT4();                                                                  \
    SBAR();                                                                    \
    for (int kt = 0; kt < (NT); kt++) {                                        \
        const int buf = kt & 1, ob = buf ^ 1;                                  \
        const int tp1 = (kt + 1 < (NT)) ? kt + 1 : 0;                          \
        const int tp2 = (kt + 2 < (NT)) ? kt + 2 : kt + 2 - (NT);              \
        bf16x8 a0, a1, a2, a3, bb0, bb1, bb2, bb3, cc0, cc1, cc2, cc3;         \
        /* ph1 */                                                              \
        a0 = LDA(0, 0); a1 = LDA(1, 0); a2 = LDA(2, 0); a3 = LDA(3, 0);        \
        bb0 = LDB(0, 0); bb1 = LDB(1, 0); bb2 = LDB(2, 0); bb3 = LDB(3, 0);    \
        STAGE_B(ob, 0, tp1);                                                   \
        VMCNT4();                                                              \
        SBAR();                                                                \
        __builtin_amdgcn_s_setprio(1);                                         \
        MM4(0, a0, bb0, bb1, bb2, bb3); MM4(1, a1, bb0, bb1, bb2, bb3);        \
        MM4(2, a2, bb0, bb1, bb2, bb3); MM4(3, a3, bb0, bb1, bb2, bb3);        \
        __builtin_amdgcn_s_setprio(0);                                         \
        SBAR();                                                                \
        /* ph2 */                                                              \
        a0 = LDA(4, 0); a1 = LDA(5, 0); a2 = LDA(6, 0); a3 = LDA(7, 0);        \
        STAGE_B(ob, 1, tp1);                                                   \
        SBAR();                                                                \
        __builtin_amdgcn_s_setprio(1);                                         \
        MM4(4, a0, bb0, bb1, bb2, bb3); MM4(5, a1, bb0, bb1, bb2, bb3);        \
        MM4(6, a2, bb0, bb1, bb2, bb3); MM4(7, a3, bb0, bb1, bb2, bb3);        \
        __builtin_amdgcn_s_setprio(0);                                         \
        SBAR();                                                                \
        /* ph3 */                                                              \
        a0 = LDA(0, 1); a1 = LDA(1, 1); a2 = LDA(2, 1); a3 = LDA(3, 1);        \
        cc0 = LDB(0, 1); cc1 = LDB(1, 1); cc2 = LDB(2, 1); cc3 = LDB(3, 1);    \
        STAGE_A(ob, 1, tp1);                                                   \
        SBAR();                                                                \
        __builtin_amdgcn_s_setprio(1);                                         \
        MM4(0, a0, cc0, cc1, cc2, cc3); MM4(1, a1, cc0, cc1, cc2, cc3);        \
        MM4(2, a2, cc0, cc1, cc2, cc3); MM4(3, a3, cc0, cc1, cc2, cc3);        \
        __builtin_amdgcn_s_setprio(0);                                         \
        SBAR();                                                                \
        /* ph4 */                                                              \
        a0 = LDA(4, 1); a1 = LDA(5, 1); a2 = LDA(6, 1); a3 = LDA(7, 1);        \
        STAGE_A(buf, 0, tp2);                                                  \
        VMCNT4();                                                              \
        SBAR();                                                                \
        __builtin_amdgcn_s_setprio(1);                                         \
        MM4(4, a0, cc0, cc1, cc2, cc3); MM4(5, a1, cc0, cc1, cc2, cc3);        \
        MM4(6, a2, cc0, cc1, cc2, cc3); MM4(7, a3, cc0, cc1, cc2, cc3);        \
        __builtin_amdgcn_s_setprio(0);                                         \
        SBAR();                                                                \
    }                                                                          \
    VMCNT0(); /* drain before LDS dealloc / epilogue */                        \
} while (0)

// ---------------- gating ----------------
__global__ __launch_bounds__(64) void gate_kernel(
    const float* __restrict__ x, const float* __restrict__ Wg,
    const float* __restrict__ bg, float* __restrict__ out_probs,
    float* __restrict__ out_idx, int* __restrict__ cnt, int* __restrict__ list)
{
    const int t = blockIdx.x;
    const int l = threadIdx.x;
    double part[E_NUM];
#pragma unroll
    for (int e = 0; e < E_NUM; e++) part[e] = 0.0;
    const float* xr = x + (size_t)t * D_DIM;
#pragma unroll
    for (int i = 0; i < D_DIM / 64; i++) {
        const int d = l + i * 64;
        const float xv = xr[d];
        const float* wr = Wg + (size_t)d * E_NUM;
        float4 w0 = *(const float4*)(wr);
        float4 w1 = *(const float4*)(wr + 4);
        part[0] += (double)xv * (double)w0.x;
        part[1] += (double)xv * (double)w0.y;
        part[2] += (double)xv * (double)w0.z;
        part[3] += (double)xv * (double)w0.w;
        part[4] += (double)xv * (double)w1.x;
        part[5] += (double)xv * (double)w1.y;
        part[6] += (double)xv * (double)w1.z;
        part[7] += (double)xv * (double)w1.w;
    }
#pragma unroll
    for (int e = 0; e < E_NUM; e++) {
        double v = part[e];
        for (int s = 32; s > 0; s >>= 1) v += __shfl_xor(v, s, 64);
        part[e] = v;
    }
    if (l == 0) {
        float logits[E_NUM], probs[E_NUM];
        float m = -3.0e38f;
#pragma unroll
        for (int e = 0; e < E_NUM; e++) {
            logits[e] = (float)(part[e] + (double)bg[e]);
            m = fmaxf(m, logits[e]);
        }
        float s = 0.f;
#pragma unroll
        for (int e = 0; e < E_NUM; e++) { probs[e] = expf(logits[e] - m); s += probs[e]; }
        const float inv = 1.f / s;
        int best = 0; float bp = -1.f;
#pragma unroll
        for (int e = 0; e < E_NUM; e++) {
            probs[e] *= inv;
            if (probs[e] > bp) { bp = probs[e]; best = e; }
        }
#pragma unroll
        for (int e = 0; e < E_NUM; e++) out_probs[(size_t)t * E_NUM + e] = probs[e];
        out_idx[t] = (float)best;
        const int pos = atomicAdd(&cnt[best], 1);
        list[best * NTOK + pos] = t;
    }
}

__global__ void zero_cnt_kernel(int* cnt)
{
    if (threadIdx.x < E_NUM) cnt[threadIdx.x] = 0;
}

// prefix offsets + compact row-tile table (expert, local row0 of each 256-row tile)
__global__ void offsets_kernel(const int* __restrict__ cnt, int* __restrict__ off,
                               int* __restrict__ tile_e, int* __restrict__ tile_row,
                               int* __restrict__ tile_n)
{
    if (threadIdx.x == 0) {
        int a = 0, n = 0;
        for (int e = 0; e < E_NUM; e++) {
            off[e] = a; a += cnt[e];
            for (int rr = 0; rr < cnt[e]; rr += BM) {
                tile_e[n] = e; tile_row[n] = rr; n++;
            }
        }
        tile_n[0] = n;
    }
}

// gather routed x rows into bf16, contiguous per expert
__global__ __launch_bounds__(256) void gather_kernel(
    const float* __restrict__ x, const int* __restrict__ off,
    const int* __restrict__ cnt, const int* __restrict__ list,
    bf16* __restrict__ Xg)
{
    const int p = blockIdx.x;
    int e = 0;
    while (e < E_NUM - 1 && p >= off[e] + cnt[e]) e++;
    const int token = list[e * NTOK + (p - off[e])];
    const float* src = x + (size_t)token * D_DIM;
    bf16* dst = Xg + (size_t)p * D_DIM;
    const int t = threadIdx.x;
    float4 v = *(const float4*)(src + t * 4);
    bf16x4 o;
    o[0] = (bf16)v.x; o[1] = (bf16)v.y; o[2] = (bf16)v.z; o[3] = (bf16)v.w;
    *(bf16x4*)(dst + t * 4) = o;
}

// transpose+convert one [K][N] fp32 matrix (per expert) to [N][K] bf16. 64x64 tiles.
__global__ __launch_bounds__(256) void transpose_conv_kernel(
    const float* __restrict__ in, bf16* __restrict__ out, int K, int N)
{
    const int e = blockIdx.z;
    const float* src = in + (size_t)e * K * N;
    bf16* dst = out + (size_t)e * K * N;
    __shared__ float T[64][65];
    const int t = threadIdx.x;
    const int k0 = blockIdx.x * 64, n0 = blockIdx.y * 64;
    {
        const int ty = t >> 4;
        const int tx = (t & 15) * 4;
#pragma unroll
        for (int i = 0; i < 4; i++) {
            float4 v = *(const float4*)(src + (size_t)(k0 + ty + 16 * i) * N + n0 + tx);
            T[ty + 16 * i][tx + 0] = v.x; T[ty + 16 * i][tx + 1] = v.y;
            T[ty + 16 * i][tx + 2] = v.z; T[ty + 16 * i][tx + 3] = v.w;
        }
    }
    __syncthreads();
    {
        const int n  = t >> 2;
        const int kx = (t & 3) * 16;
        bf16 tmp[16];
#pragma unroll
        for (int j = 0; j < 16; j++) tmp[j] = (bf16)T[kx + j][n];
        *(bf16x8*)(dst + (size_t)(n0 + n) * K + k0 + kx)     = *(bf16x8*)&tmp[0];
        *(bf16x8*)(dst + (size_t)(n0 + n) * K + k0 + kx + 8) = *(bf16x8*)&tmp[8];
    }
}

// partial sums of c[e][d] = relu(b1[e]) . W2[e][:,d]
__global__ __launch_bounds__(256) void cpart_kernel(
    const float* __restrict__ W2, const float* __restrict__ b1,
    float* __restrict__ cpart)
{
    const int chunk = blockIdx.x;
    const int e = blockIdx.y;
    const int t = threadIdx.x;
    float acc0 = 0.f, acc1 = 0.f, acc2 = 0.f, acc3 = 0.f;
    for (int hh = 0; hh < H_DIM / 32; hh++) {
        const int h = chunk * (H_DIM / 32) + hh;
        const float rb = fmaxf(b1[(size_t)e * H_DIM + h], 0.f);
        float4 w = *(const float4*)(W2 + ((size_t)e * H_DIM + h) * D_DIM + t * 4);
        acc0 += rb * w.x; acc1 += rb * w.y; acc2 += rb * w.z; acc3 += rb * w.w;
    }
    float* dst = cpart + ((size_t)(e * 32 + chunk)) * D_DIM + t * 4;
    dst[0] = acc0; dst[1] = acc1; dst[2] = acc2; dst[3] = acc3;
}

__global__ __launch_bounds__(256) void cfinal_kernel(
    const float* __restrict__ cpart, const float* __restrict__ b2,
    float* __restrict__ adj)
{
    const int d = blockIdx.x * 256 + threadIdx.x;
    float c[E_NUM];
    float tot = 0.f;
#pragma unroll
    for (int e = 0; e < E_NUM; e++) {
        float s = 0.f;
        for (int ch = 0; ch < 32; ch++) s += cpart[((size_t)(e * 32 + ch)) * D_DIM + d];
        s += b2[(size_t)e * D_DIM + d];
        c[e] = s; tot += s;
    }
#pragma unroll
    for (int e = 0; e < E_NUM; e++) adj[(size_t)e * D_DIM + d] = tot - c[e];
}

// ---------------- grouped GEMM 1 (8-phase 256x256, counted vmcnt): h = relu(Xg @ W1t^T + b1) ----------------
__global__ __launch_bounds__(512, 2) void gemm1_kernel(
    const bf16* __restrict__ Xg, const bf16* __restrict__ W1t,
    const float* __restrict__ b1, const int* __restrict__ cnt,
    const int* __restrict__ off, const int* __restrict__ tile_e,
    const int* __restrict__ tile_row, const int* __restrict__ tile_n,
    bf16* __restrict__ Hb)
{
    const int orig = blockIdx.x;
    const int qch = (MAXT * NBY1) >> 3;        // 640/8 = 80
    const int fid = (orig & 7) * qch + (orig >> 3);
    const int tx = fid % MAXT;
    const int by = fid / MAXT;
    if (tx >= tile_n[0]) return;
    const int e  = tile_e[tx];
    const int m0 = tile_row[tx];
    const int ne = cnt[e];
    const int oe = off[e];
    const int K = D_DIM;

    __shared__ bf16 sA[2][BM * BK];
    __shared__ bf16 sB[2][BN * BK];

    const int t = threadIdx.x;
    const int w = t >> 6, lane = t & 63;
    const int wr = w >> 2, wc = w & 3;         // 2M x 4N waves
    const int l15 = lane & 15;
    // T2 read-side swizzle: chunk' = (kh*4 + lane>>4) ^ (lane&7), elems = chunk'*8
    const int kidx0 = (((lane >> 4)) ^ (lane & 7)) << 3;
    const int kidx1 = ((4 + (lane >> 4)) ^ (lane & 7)) << 3;

    const int srow = t >> 3;                   // 0..63
    // T2 write-side: pre-swizzled GLOBAL source chunk (LDS dest stays linear)
    const int schk = (((t & 7) ^ ((t >> 3) & 7)) << 3);
    const bf16* Asrc = Xg + (size_t)(oe + m0 + srow) * K + schk;
    const bf16* Bsrc = W1t + ((size_t)e * H_DIM + by * BN + srow) * K + schk;

    f32x4 acc[8][4];
#pragma unroll
    for (int i = 0; i < 8; i++)
#pragma unroll
        for (int j = 0; j < 4; j++) acc[i][j] = (f32x4){0.f, 0.f, 0.f, 0.f};

    KLOOP(K / BK);

    // epilogue: bias + relu -> Hb (bf16)
    float bias[4];
#pragma unroll
    for (int j = 0; j < 4; j++)
        bias[j] = b1[(size_t)e * H_DIM + by * BN + wc * 64 + j * 16 + l15];
#pragma unroll
    for (int i = 0; i < 8; i++) {
        const int rb0 = m0 + i * 32 + wr * 16 + ((lane >> 4) << 2);
#pragma unroll
        for (int j = 0; j < 4; j++) {
            const int gcol = by * BN + wc * 64 + j * 16 + l15;
#pragma unroll
            for (int r = 0; r < 4; r++) {
                const int grow = rb0 + r;
                if (grow < ne) {
                    float v = acc[i][j][r] + bias[j];
                    Hb[((size_t)(oe + grow)) * H_DIM + gcol] = (bf16)fmaxf(v, 0.f);
                }
            }
        }
    }
}

// ---------------- grouped GEMM 2 (8-phase 256x256, counted vmcnt): out = h @ W2t^T + b2 + adj ----------------
__global__ __launch_bounds__(512, 2) void gemm2_kernel(
    const bf16* __restrict__ Hb, const bf16* __restrict__ W2t,
    const float* __restrict__ b2, const float* __restrict__ adj,
    const int* __restrict__ cnt, const int* __restrict__ off,
    const int* __restrict__ tile_e, const int* __restrict__ tile_row,
    const int* __restrict__ tile_n, const int* __restrict__ list,
    float* __restrict__ out)
{
    const int orig = blockIdx.x;
    const int qch = (MAXT * NBY2) >> 3;        // 160/8 = 20
    const int fid = (orig & 7) * qch + (orig >> 3);
    const int tx = fid % MAXT;
    const int by = fid / MAXT;
    if (tx >= tile_n[0]) return;
    const int e  = tile_e[tx];
    const int m0 = tile_row[tx];
    const int ne = cnt[e];
    const int oe = off[e];
    const int K = H_DIM;

    __shared__ bf16 sA[2][BM * BK];
    __shared__ bf16 sB[2][BN * BK];

    const int t = threadIdx.x;
    const int w = t >> 6, lane = t & 63;
    const int wr = w >> 2, wc = w & 3;
    const int l15 = lane & 15;
    const int kidx0 = (((lane >> 4)) ^ (lane & 7)) << 3;
    const int kidx1 = ((4 + (lane >> 4)) ^ (lane & 7)) << 3;

    const int srow = t >> 3;
    const int schk = (((t & 7) ^ ((t >> 3) & 7)) << 3);
    const bf16* Asrc = Hb + (size_t)(oe + m0 + srow) * K + schk;
    const bf16* Bsrc = W2t + ((size_t)e * D_DIM + by * BN + srow) * K + schk;

    f32x4 acc[8][4];
#pragma unroll
    for (int i = 0; i < 8; i++)
#pragma unroll
        for (int j = 0; j < 4; j++) acc[i][j] = (f32x4){0.f, 0.f, 0.f, 0.f};

    KLOOP(K / BK);

    float badj[4];
#pragma unroll
    for (int j = 0; j < 4; j++) {
        const int gcol = by * BN + wc * 64 + j * 16 + l15;
        badj[j] = b2[(size_t)e * D_DIM + gcol] + adj[(size_t)e * D_DIM + gcol];
    }
#pragma unroll
    for (int i = 0; i < 8; i++) {
        const int rb0 = m0 + i * 32 + wr * 16 + ((lane >> 4) << 2);
#pragma unroll
        for (int j = 0; j < 4; j++) {
            const int gcol = by * BN + wc * 64 + j * 16 + l15;
#pragma unroll
            for (int r = 0; r < 4; r++) {
                const int grow = rb0 + r;
                if (grow < ne) {
                    const int tok = list[e * NTOK + grow];
                    out[(size_t)tok * D_DIM + gcol] = acc[i][j][r] + badj[j];
                }
            }
        }
    }
}

extern "C" void kernel_launch(void* const* d_in, const int* in_sizes, int n_in,
                              void* d_out, int out_size, void* d_ws, size_t ws_size,
                              hipStream_t stream)
{
    (void)in_sizes; (void)n_in; (void)out_size; (void)ws_size;
    const float* x  = (const float*)d_in[0];
    const float* Wg = (const float*)d_in[1];
    const float* bg = (const float*)d_in[2];
    const float* W1 = (const float*)d_in[3];
    const float* b1 = (const float*)d_in[4];
    const float* W2 = (const float*)d_in[5];
    const float* b2 = (const float*)d_in[6];

    float* out_comb  = (float*)d_out;
    float* out_probs = out_comb + (size_t)NTOK * D_DIM;
    float* out_idx   = out_probs + (size_t)NTOK * E_NUM;

    // ws layout: GEMM A-staging can overread up to 255 rows past the end of
    // Xg (510 KB) and Hb (2 MB) — Xg is followed by cpart+adj+lists (>1.3 MB)
    // and Hb by Xg (16 MB), so all overshoot stays inside d_ws (values unused:
    // rows >= ne are never written out).
    char* ws = (char*)d_ws;
    size_t o = 0;
    bf16* W1t = (bf16*)(ws + o); o += (size_t)E_NUM * H_DIM * D_DIM * 2;  // 64MB
    bf16* W2t = (bf16*)(ws + o); o += (size_t)E_NUM * H_DIM * D_DIM * 2;  // 64MB
    bf16* Hb  = (bf16*)(ws + o); o += (size_t)NTOK * H_DIM * 2;           // 64MB
    bf16* Xg  = (bf16*)(ws + o); o += (size_t)NTOK * D_DIM * 2;           // 16MB
    float* cpart = (float*)(ws + o); o += (size_t)E_NUM * 32 * D_DIM * 4; // 1MB
    float* adj   = (float*)(ws + o); o += (size_t)E_NUM * D_DIM * 4;      // 32KB
    int* cnt  = (int*)(ws + o); o += 256;
    int* off  = (int*)(ws + o); o += 256;
    int* tile_e   = (int*)(ws + o); o += 512;
    int* tile_row = (int*)(ws + o); o += 512;
    int* tile_n   = (int*)(ws + o); o += 256;
    int* list = (int*)(ws + o); o += (size_t)E_NUM * NTOK * 4;            // 256KB

    zero_cnt_kernel<<<1, 64, 0, stream>>>(cnt);
    gate_kernel<<<NTOK, 64, 0, stream>>>(x, Wg, bg, out_probs, out_idx, cnt, list);
    offsets_kernel<<<1, 64, 0, stream>>>(cnt, off, tile_e, tile_row, tile_n);
    gather_kernel<<<NTOK, 256, 0, stream>>>(x, off, cnt, list, Xg);
    transpose_conv_kernel<<<dim3(D_DIM / 64, H_DIM / 64, E_NUM), 256, 0, stream>>>(W1, W1t, D_DIM, H_DIM);
    transpose_conv_kernel<<<dim3(H_DIM / 64, D_DIM / 64, E_NUM), 256, 0, stream>>>(W2, W2t, H_DIM, D_DIM);
    cpart_kernel<<<dim3(32, E_NUM), 256, 0, stream>>>(W2, b1, cpart);
    cfinal_kernel<<<D_DIM / 256, 256, 0, stream>>>(cpart, b2, adj);
    gemm1_kernel<<<MAXT * NBY1, 512, 0, stream>>>(Xg, W1t, b1, cnt, off, tile_e, tile_row, tile_n, Hb);
    gemm2_kernel<<<MAXT * NBY2, 512, 0, stream>>>(Hb, W2t, b2, adj, cnt, off, tile_e, tile_row, tile_n, list, out_comb);
}

// Round 7
// 499.093 us; speedup vs baseline: 1.4639x; 1.1221x over previous
//
#include <hip/hip_runtime.h>
#include <hip/hip_bf16.h>
#include <cstdint>

#define D_DIM 1024
#define H_DIM 4096
#define E_NUM 8
#define NTOK  8192

#define BM 128
#define BN 128
#define BK 64

#define MAXT 72             // worst-case 128-row tiles: sum ceil(ne/128) <= 71
#define NBY1 (H_DIM / BN)   // 32
#define NBY2 (D_DIM / BN)   // 8

typedef __bf16 bf16;
typedef __bf16 bf16x8 __attribute__((ext_vector_type(8)));
typedef __bf16 bf16x4 __attribute__((ext_vector_type(4)));
typedef float  f32x4  __attribute__((ext_vector_type(4)));

// global_load_lds: per-lane global src, wave-uniform LDS base + lane*16B dest
#define GLOAD16(g, l)                                                          \
    __builtin_amdgcn_global_load_lds(                                          \
        (const __attribute__((address_space(1))) void*)(g),                    \
        (__attribute__((address_space(3))) void*)(l), 16, 0, 0)

// Raw barrier (no implicit vmcnt(0) drain, unlike __syncthreads)
#define SBAR()   asm volatile("s_barrier" ::: "memory")
#define VMCNT0() asm volatile("s_waitcnt vmcnt(0)" ::: "memory")

// ---- 128x128 BK=64 GEMM blocks, 4 waves (2M x 2N), 64KB LDS -> 2 blocks/CU.
// T2 XOR-swizzle: stored(row,chunk) = logical(row, chunk^(row&7)); write side
// pre-swizzles the GLOBAL source chunk (LDS dest linear for global_load_lds);
// read side XORs chunk with row&7 (== lane&7 for fragment rows).
// Staging: 4 GLOAD16 per matrix per K-tile; wave w call g covers rows
// w*8+g*32 .. +7 (lane l -> row +(l>>3), src chunk (l&7)^(l>>3), dest linear).
#define STAGE_A(bf, tt) do {                                                   \
    GLOAD16(Asrc + (size_t)(tt) * BK,               &sA[(bf)][(w * 8) * BK]);  \
    GLOAD16(Asrc + 32 * K + (size_t)(tt) * BK,      &sA[(bf)][(w * 8 + 32) * BK]); \
    GLOAD16(Asrc + 64 * K + (size_t)(tt) * BK,      &sA[(bf)][(w * 8 + 64) * BK]); \
    GLOAD16(Asrc + 96 * K + (size_t)(tt) * BK,      &sA[(bf)][(w * 8 + 96) * BK]); \
} while (0)
#define STAGE_B(bf, tt) do {                                                   \
    GLOAD16(Bsrc + (size_t)(tt) * BK,               &sB[(bf)][(w * 8) * BK]);  \
    GLOAD16(Bsrc + 32 * K + (size_t)(tt) * BK,      &sB[(bf)][(w * 8 + 32) * BK]); \
    GLOAD16(Bsrc + 64 * K + (size_t)(tt) * BK,      &sB[(bf)][(w * 8 + 64) * BK]); \
    GLOAD16(Bsrc + 96 * K + (size_t)(tt) * BK,      &sB[(bf)][(w * 8 + 96) * BK]); \
} while (0)

// fragment reads: A row = wr*64 + i*16 + l15; B row = wc*64 + j*16 + l15
#define LDA(i, kh) (*(const bf16x8*)&sA[buf][((i) * 16 + wr * 64 + l15) * BK + ((kh) ? kidx1 : kidx0)])
#define LDB(j, kh) (*(const bf16x8*)&sB[buf][((j) * 16 + wc * 64 + l15) * BK + ((kh) ? kidx1 : kidx0)])

#define MMROW(I, AA) do {                                                      \
    acc[I][0] = __builtin_amdgcn_mfma_f32_16x16x32_bf16(AA, vb0, acc[I][0], 0, 0, 0); \
    acc[I][1] = __builtin_amdgcn_mfma_f32_16x16x32_bf16(AA, vb1, acc[I][1], 0, 0, 0); \
    acc[I][2] = __builtin_amdgcn_mfma_f32_16x16x32_bf16(AA, vb2, acc[I][2], 0, 0, 0); \
    acc[I][3] = __builtin_amdgcn_mfma_f32_16x16x32_bf16(AA, vb3, acc[I][3], 0, 0, 0); \
} while (0)

// K-loop: 2 phases/tile, pure next-tile staging into ob (no intra-buffer
// hazards; tile-end barrier after each wave's own vmcnt(0) makes all staged
// writes visible before tile t+1 reads ob). 2 blocks/CU provide the TLP that
// covers the ~1-phase-short drain slack.
#define KLOOP(NT) do {                                                         \
    STAGE_A(0, 0); STAGE_B(0, 0);                                              \
    VMCNT0(); SBAR();                                                          \
    for (int kt = 0; kt < (NT); kt++) {                                        \
        const int buf = kt & 1, ob = buf ^ 1;                                  \
        const int tp1 = (kt + 1 < (NT)) ? kt + 1 : 0;                          \
        bf16x8 a0, a1, a2, a3, vb0, vb1, vb2, vb3;                             \
        /* ph1: k-half 0 */                                                    \
        a0 = LDA(0, 0); a1 = LDA(1, 0); a2 = LDA(2, 0); a3 = LDA(3, 0);        \
        vb0 = LDB(0, 0); vb1 = LDB(1, 0); vb2 = LDB(2, 0); vb3 = LDB(3, 0);    \
        STAGE_B(ob, tp1);                                                      \
        SBAR();                                                                \
        __builtin_amdgcn_s_setprio(1);                                         \
        MMROW(0, a0); MMROW(1, a1); MMROW(2, a2); MMROW(3, a3);                \
        __builtin_amdgcn_s_setprio(0);                                         \
        SBAR();                                                                \
        /* ph2: k-half 1 */                                                    \
        a0 = LDA(0, 1); a1 = LDA(1, 1); a2 = LDA(2, 1); a3 = LDA(3, 1);        \
        vb0 = LDB(0, 1); vb1 = LDB(1, 1); vb2 = LDB(2, 1); vb3 = LDB(3, 1);    \
        STAGE_A(ob, tp1);                                                      \
        SBAR();                                                                \
        __builtin_amdgcn_s_setprio(1);                                         \
        MMROW(0, a0); MMROW(1, a1); MMROW(2, a2); MMROW(3, a3);                \
        __builtin_amdgcn_s_setprio(0);                                         \
        VMCNT0();                                                              \
        SBAR();                                                                \
    }                                                                          \
} while (0)

// ---------------- gating ----------------
__global__ __launch_bounds__(64) void gate_kernel(
    const float* __restrict__ x, const float* __restrict__ Wg,
    const float* __restrict__ bg, float* __restrict__ out_probs,
    float* __restrict__ out_idx, int* __restrict__ cnt, int* __restrict__ list)
{
    const int t = blockIdx.x;
    const int l = threadIdx.x;
    double part[E_NUM];
#pragma unroll
    for (int e = 0; e < E_NUM; e++) part[e] = 0.0;
    const float* xr = x + (size_t)t * D_DIM;
#pragma unroll
    for (int i = 0; i < D_DIM / 64; i++) {
        const int d = l + i * 64;
        const float xv = xr[d];
        const float* wr = Wg + (size_t)d * E_NUM;
        float4 w0 = *(const float4*)(wr);
        float4 w1 = *(const float4*)(wr + 4);
        part[0] += (double)xv * (double)w0.x;
        part[1] += (double)xv * (double)w0.y;
        part[2] += (double)xv * (double)w0.z;
        part[3] += (double)xv * (double)w0.w;
        part[4] += (double)xv * (double)w1.x;
        part[5] += (double)xv * (double)w1.y;
        part[6] += (double)xv * (double)w1.z;
        part[7] += (double)xv * (double)w1.w;
    }
#pragma unroll
    for (int e = 0; e < E_NUM; e++) {
        double v = part[e];
        for (int s = 32; s > 0; s >>= 1) v += __shfl_xor(v, s, 64);
        part[e] = v;
    }
    if (l == 0) {
        float logits[E_NUM], probs[E_NUM];
        float m = -3.0e38f;
#pragma unroll
        for (int e = 0; e < E_NUM; e++) {
            logits[e] = (float)(part[e] + (double)bg[e]);
            m = fmaxf(m, logits[e]);
        }
        float s = 0.f;
#pragma unroll
        for (int e = 0; e < E_NUM; e++) { probs[e] = expf(logits[e] - m); s += probs[e]; }
        const float inv = 1.f / s;
        int best = 0; float bp = -1.f;
#pragma unroll
        for (int e = 0; e < E_NUM; e++) {
            probs[e] *= inv;
            if (probs[e] > bp) { bp = probs[e]; best = e; }
        }
#pragma unroll
        for (int e = 0; e < E_NUM; e++) out_probs[(size_t)t * E_NUM + e] = probs[e];
        out_idx[t] = (float)best;
        const int pos = atomicAdd(&cnt[best], 1);
        list[best * NTOK + pos] = t;
    }
}

// zero cnt + cpartial
__global__ __launch_bounds__(256) void zero_kernel(int* cnt, float* cpartial)
{
    const int i = blockIdx.x * 256 + threadIdx.x;
    if (i < E_NUM * D_DIM) cpartial[i] = 0.f;
    if (i < E_NUM) cnt[i] = 0;
}

// prefix offsets + compact row-tile table (expert, local row0 of each 128-row tile)
__global__ void offsets_kernel(const int* __restrict__ cnt, int* __restrict__ off,
                               int* __restrict__ tile_e, int* __restrict__ tile_row,
                               int* __restrict__ tile_n)
{
    if (threadIdx.x == 0) {
        int a = 0, n = 0;
        for (int e = 0; e < E_NUM; e++) {
            off[e] = a; a += cnt[e];
            for (int rr = 0; rr < cnt[e]; rr += BM) {
                tile_e[n] = e; tile_row[n] = rr; n++;
            }
        }
        tile_n[0] = n;
    }
}

// gather routed x rows into bf16, contiguous per expert
__global__ __launch_bounds__(256) void gather_kernel(
    const float* __restrict__ x, const int* __restrict__ off,
    const int* __restrict__ cnt, const int* __restrict__ list,
    bf16* __restrict__ Xg)
{
    const int p = blockIdx.x;
    int e = 0;
    while (e < E_NUM - 1 && p >= off[e] + cnt[e]) e++;
    const int token = list[e * NTOK + (p - off[e])];
    const float* src = x + (size_t)token * D_DIM;
    bf16* dst = Xg + (size_t)p * D_DIM;
    const int t = threadIdx.x;
    float4 v = *(const float4*)(src + t * 4);
    bf16x4 o;
    o[0] = (bf16)v.x; o[1] = (bf16)v.y; o[2] = (bf16)v.z; o[3] = (bf16)v.w;
    *(bf16x4*)(dst + t * 4) = o;
}

// transpose+convert one [K][N] fp32 matrix (per expert) to [N][K] bf16. 64x64 tiles.
__global__ __launch_bounds__(256) void transpose_conv_kernel(
    const float* __restrict__ in, bf16* __restrict__ out, int K, int N)
{
    const int e = blockIdx.z;
    const float* src = in + (size_t)e * K * N;
    bf16* dst = out + (size_t)e * K * N;
    __shared__ float T[64][65];
    const int t = threadIdx.x;
    const int k0 = blockIdx.x * 64, n0 = blockIdx.y * 64;
    {
        const int ty = t >> 4;
        const int tx = (t & 15) * 4;
#pragma unroll
        for (int i = 0; i < 4; i++) {
            float4 v = *(const float4*)(src + (size_t)(k0 + ty + 16 * i) * N + n0 + tx);
            T[ty + 16 * i][tx + 0] = v.x; T[ty + 16 * i][tx + 1] = v.y;
            T[ty + 16 * i][tx + 2] = v.z; T[ty + 16 * i][tx + 3] = v.w;
        }
    }
    __syncthreads();
    {
        const int n  = t >> 2;
        const int kx = (t & 3) * 16;
        bf16 tmp[16];
#pragma unroll
        for (int j = 0; j < 16; j++) tmp[j] = (bf16)T[kx + j][n];
        *(bf16x8*)(dst + (size_t)(n0 + n) * K + k0 + kx)     = *(bf16x8*)&tmp[0];
        *(bf16x8*)(dst + (size_t)(n0 + n) * K + k0 + kx + 8) = *(bf16x8*)&tmp[8];
    }
}

// W2 variant: transpose+convert AND accumulate cpartial[e][d] += relu(b1).W2 tile
__global__ __launch_bounds__(256) void transpose_conv_w2_kernel(
    const float* __restrict__ in, const float* __restrict__ b1,
    bf16* __restrict__ out, float* __restrict__ cpartial)
{
    const int K = H_DIM, N = D_DIM;
    const int e = blockIdx.z;
    const float* src = in + (size_t)e * K * N;
    bf16* dst = out + (size_t)e * K * N;
    __shared__ float T[64][65];
    const int t = threadIdx.x;
    const int k0 = blockIdx.x * 64, n0 = blockIdx.y * 64;
    {
        const int ty = t >> 4;
        const int tx = (t & 15) * 4;
#pragma unroll
        for (int i = 0; i < 4; i++) {
            float4 v = *(const float4*)(src + (size_t)(k0 + ty + 16 * i) * N + n0 + tx);
            T[ty + 16 * i][tx + 0] = v.x; T[ty + 16 * i][tx + 1] = v.y;
            T[ty + 16 * i][tx + 2] = v.z; T[ty + 16 * i][tx + 3] = v.w;
        }
    }
    __syncthreads();
    {
        const int n  = t >> 2;
        const int kx = (t & 3) * 16;
        bf16 tmp[16];
#pragma unroll
        for (int j = 0; j < 16; j++) tmp[j] = (bf16)T[kx + j][n];
        *(bf16x8*)(dst + (size_t)(n0 + n) * K + k0 + kx)     = *(bf16x8*)&tmp[0];
        *(bf16x8*)(dst + (size_t)(n0 + n) * K + k0 + kx + 8) = *(bf16x8*)&tmp[8];
    }
    // fused cpart: c[e][d] partial over this h-tile (saves a 128MB re-read of W2)
    if (t < 64) {
        float s = 0.f;
#pragma unroll 8
        for (int h = 0; h < 64; h++)
            s += fmaxf(b1[(size_t)e * H_DIM + k0 + h], 0.f) * T[h][t];
        atomicAdd(&cpartial[(size_t)e * D_DIM + n0 + t], s);
    }
}

__global__ __launch_bounds__(256) void cfinal_kernel(
    const float* __restrict__ cpartial, const float* __restrict__ b2,
    float* __restrict__ adj)
{
    const int d = blockIdx.x * 256 + threadIdx.x;
    float c[E_NUM];
    float tot = 0.f;
#pragma unroll
    for (int e = 0; e < E_NUM; e++) {
        c[e] = cpartial[(size_t)e * D_DIM + d] + b2[(size_t)e * D_DIM + d];
        tot += c[e];
    }
#pragma unroll
    for (int e = 0; e < E_NUM; e++) adj[(size_t)e * D_DIM + d] = tot - c[e];
}

// ---------------- grouped GEMM 1 (128x128, 2 blocks/CU): h = relu(Xg @ W1t^T + b1) ----------------
__global__ __launch_bounds__(256, 2) void gemm1_kernel(
    const bf16* __restrict__ Xg, const bf16* __restrict__ W1t,
    const float* __restrict__ b1, const int* __restrict__ cnt,
    const int* __restrict__ off, const int* __restrict__ tile_e,
    const int* __restrict__ tile_row, const int* __restrict__ tile_n,
    bf16* __restrict__ Hb)
{
    const int orig = blockIdx.x;
    const int qch = (MAXT * NBY1) >> 3;        // 2304/8 = 288
    const int fid = (orig & 7) * qch + (orig >> 3);
    const int tx = fid % MAXT;
    const int by = fid / MAXT;
    if (tx >= tile_n[0]) return;
    const int e  = tile_e[tx];
    const int m0 = tile_row[tx];
    const int ne = cnt[e];
    const int oe = off[e];
    const int K = D_DIM;

    __shared__ bf16 sA[2][BM * BK];
    __shared__ bf16 sB[2][BN * BK];

    const int t = threadIdx.x;
    const int w = t >> 6, lane = t & 63;
    const int wr = w >> 1, wc = w & 1;         // 2M x 2N waves
    const int l15 = lane & 15;
    const int kidx0 = (((lane >> 4)) ^ (lane & 7)) << 3;
    const int kidx1 = ((4 + (lane >> 4)) ^ (lane & 7)) << 3;

    // staging source: row = w*8 + (lane>>3) (+32 per call), chunk pre-swizzled
    const int srow = w * 8 + (lane >> 3);
    const int schk = (((lane & 7) ^ (lane >> 3)) << 3);
    const bf16* Asrc = Xg + (size_t)(oe + m0 + srow) * K + schk;
    const bf16* Bsrc = W1t + ((size_t)e * H_DIM + by * BN + srow) * K + schk;

    f32x4 acc[4][4];
#pragma unroll
    for (int i = 0; i < 4; i++)
#pragma unroll
        for (int j = 0; j < 4; j++) acc[i][j] = (f32x4){0.f, 0.f, 0.f, 0.f};

    KLOOP(K / BK);

    float bias[4];
#pragma unroll
    for (int j = 0; j < 4; j++)
        bias[j] = b1[(size_t)e * H_DIM + by * BN + wc * 64 + j * 16 + l15];
#pragma unroll
    for (int i = 0; i < 4; i++) {
        const int rb0 = m0 + wr * 64 + i * 16 + ((lane >> 4) << 2);
#pragma unroll
        for (int j = 0; j < 4; j++) {
            const int gcol = by * BN + wc * 64 + j * 16 + l15;
#pragma unroll
            for (int r = 0; r < 4; r++) {
                const int grow = rb0 + r;
                if (grow < ne) {
                    float v = acc[i][j][r] + bias[j];
                    Hb[((size_t)(oe + grow)) * H_DIM + gcol] = (bf16)fmaxf(v, 0.f);
                }
            }
        }
    }
}

// ---------------- grouped GEMM 2 (128x128, 2 blocks/CU): out = h @ W2t^T + b2 + adj ----------------
__global__ __launch_bounds__(256, 2) void gemm2_kernel(
    const bf16* __restrict__ Hb, const bf16* __restrict__ W2t,
    const float* __restrict__ b2, const float* __restrict__ adj,
    const int* __restrict__ cnt, const int* __restrict__ off,
    const int* __restrict__ tile_e, const int* __restrict__ tile_row,
    const int* __restrict__ tile_n, const int* __restrict__ list,
    float* __restrict__ out)
{
    const int orig = blockIdx.x;
    const int qch = (MAXT * NBY2) >> 3;        // 576/8 = 72
    const int fid = (orig & 7) * qch + (orig >> 3);
    const int tx = fid % MAXT;
    const int by = fid / MAXT;
    if (tx >= tile_n[0]) return;
    const int e  = tile_e[tx];
    const int m0 = tile_row[tx];
    const int ne = cnt[e];
    const int oe = off[e];
    const int K = H_DIM;

    __shared__ bf16 sA[2][BM * BK];
    __shared__ bf16 sB[2][BN * BK];

    const int t = threadIdx.x;
    const int w = t >> 6, lane = t & 63;
    const int wr = w >> 1, wc = w & 1;
    const int l15 = lane & 15;
    const int kidx0 = (((lane >> 4)) ^ (lane & 7)) << 3;
    const int kidx1 = ((4 + (lane >> 4)) ^ (lane & 7)) << 3;

    const int srow = w * 8 + (lane >> 3);
    const int schk = (((lane & 7) ^ (lane >> 3)) << 3);
    const bf16* Asrc = Hb + (size_t)(oe + m0 + srow) * K + schk;
    const bf16* Bsrc = W2t + ((size_t)e * D_DIM + by * BN + srow) * K + schk;

    f32x4 acc[4][4];
#pragma unroll
    for (int i = 0; i < 4; i++)
#pragma unroll
        for (int j = 0; j < 4; j++) acc[i][j] = (f32x4){0.f, 0.f, 0.f, 0.f};

    KLOOP(K / BK);

    float badj[4];
#pragma unroll
    for (int j = 0; j < 4; j++) {
        const int gcol = by * BN + wc * 64 + j * 16 + l15;
        badj[j] = b2[(size_t)e * D_DIM + gcol] + adj[(size_t)e * D_DIM + gcol];
    }
#pragma unroll
    for (int i = 0; i < 4; i++) {
        const int rb0 = m0 + wr * 64 + i * 16 + ((lane >> 4) << 2);
#pragma unroll
        for (int j = 0; j < 4; j++) {
            const int gcol = by * BN + wc * 64 + j * 16 + l15;
#pragma unroll
            for (int r = 0; r < 4; r++) {
                const int grow = rb0 + r;
                if (grow < ne) {
                    const int tok = list[e * NTOK + grow];
                    out[(size_t)tok * D_DIM + gcol] = acc[i][j][r] + badj[j];
                }
            }
        }
    }
}

extern "C" void kernel_launch(void* const* d_in, const int* in_sizes, int n_in,
                              void* d_out, int out_size, void* d_ws, size_t ws_size,
                              hipStream_t stream)
{
    (void)in_sizes; (void)n_in; (void)out_size; (void)ws_size;
    const float* x  = (const float*)d_in[0];
    const float* Wg = (const float*)d_in[1];
    const float* bg = (const float*)d_in[2];
    const float* W1 = (const float*)d_in[3];
    const float* b1 = (const float*)d_in[4];
    const float* W2 = (const float*)d_in[5];
    const float* b2 = (const float*)d_in[6];

    float* out_comb  = (float*)d_out;
    float* out_probs = out_comb + (size_t)NTOK * D_DIM;
    float* out_idx   = out_probs + (size_t)NTOK * E_NUM;

    // ws layout: GEMM A-staging can overread up to 127 rows past the end of
    // Xg (254 KB) and Hb (1 MB) — Xg is followed by cpartial+adj+lists
    // (>1.3 MB) and Hb by Xg (16 MB), so all overshoot stays inside d_ws
    // (values unused: rows >= ne are never written out).
    char* ws = (char*)d_ws;
    size_t o = 0;
    bf16* W1t = (bf16*)(ws + o); o += (size_t)E_NUM * H_DIM * D_DIM * 2;  // 64MB
    bf16* W2t = (bf16*)(ws + o); o += (size_t)E_NUM * H_DIM * D_DIM * 2;  // 64MB
    bf16* Hb  = (bf16*)(ws + o); o += (size_t)NTOK * H_DIM * 2;           // 64MB
    bf16* Xg  = (bf16*)(ws + o); o += (size_t)NTOK * D_DIM * 2;           // 16MB
    float* cpartial = (float*)(ws + o); o += (size_t)E_NUM * D_DIM * 4;   // 32KB
    float* adj      = (float*)(ws + o); o += (size_t)E_NUM * D_DIM * 4;   // 32KB
    int* cnt  = (int*)(ws + o); o += 256;
    int* off  = (int*)(ws + o); o += 256;
    int* tile_e   = (int*)(ws + o); o += 512;
    int* tile_row = (int*)(ws + o); o += 512;
    int* tile_n   = (int*)(ws + o); o += 256;
    int* list = (int*)(ws + o); o += (size_t)E_NUM * NTOK * 4;            // 256KB

    zero_kernel<<<(E_NUM * D_DIM + 255) / 256, 256, 0, stream>>>(cnt, cpartial);
    gate_kernel<<<NTOK, 64, 0, stream>>>(x, Wg, bg, out_probs, out_idx, cnt, list);
    offsets_kernel<<<1, 64, 0, stream>>>(cnt, off, tile_e, tile_row, tile_n);
    gather_kernel<<<NTOK, 256, 0, stream>>>(x, off, cnt, list, Xg);
    transpose_conv_kernel<<<dim3(D_DIM / 64, H_DIM / 64, E_NUM), 256, 0, stream>>>(W1, W1t, D_DIM, H_DIM);
    transpose_conv_w2_kernel<<<dim3(H_DIM / 64, D_DIM / 64, E_NUM), 256, 0, stream>>>(W2, b1, W2t, cpartial);
    cfinal_kernel<<<D_DIM / 256, 256, 0, stream>>>(cpartial, b2, adj);
    gemm1_kernel<<<MAXT * NBY1, 256, 0, stream>>>(Xg, W1t, b1, cnt, off, tile_e, tile_row, tile_n, Hb);
    gemm2_kernel<<<MAXT * NBY2, 256, 0, stream>>>(Hb, W2t, b2, adj, cnt, off, tile_e, tile_row, tile_n, list, out_comb);
}